// Round 2
// baseline (581.185 us; speedup 1.0000x reference)
//
#include <hip/hip_runtime.h>
#include <hip/hip_bf16.h>

typedef __attribute__((ext_vector_type(8))) short short8;
typedef __attribute__((ext_vector_type(4))) float f32x4;

namespace {
constexpr int IN_F   = 4096;
constexpr int OUT_F  = 4096;
constexpr int TOKENS = 8192;
constexpr int PACKED = IN_F / 16;   // 256 int32 per output row

constexpr int BM   = 256;           // M tile (tokens)
constexpr int BN   = 128;           // N tile (out features)
constexpr int BK   = 64;            // K tile
constexpr int LDK  = BK + 8;        // LDS row stride (+16B pad -> conflict-free b128 frag reads)
constexpr int NTHR = 512;           // 8 waves: 4 (M) x 2 (N), each wave owns 64x64
}

// float -> bf16 bits, round-to-nearest-even (inputs are finite; no NaN path)
__device__ __forceinline__ unsigned bf16_bits(float f) {
  unsigned u = __builtin_bit_cast(unsigned, f);
  u += 0x7FFFu + ((u >> 16) & 1u);
  return u >> 16;
}

// pack two floats as bf16x2 (lo in low 16 bits)
__device__ __forceinline__ unsigned pack_bf2(float lo, float hi) {
  return bf16_bits(lo) | (bf16_bits(hi) << 16);
}

__global__ __launch_bounds__(NTHR, 4)
void pbl_kernel(const float* __restrict__ X, const int* __restrict__ PW,
                const float* __restrict__ SC, float* __restrict__ OUT) {
  // k within each 16-group is stored PERMUTED in LDS: slot 2j <- k=j, slot 2j+1 <- k=j+8.
  // Both A and B use the same permutation, so the contraction is unchanged.
  __shared__ short lA[BM * LDK];
  __shared__ short lB[BN * LDK];

  const int tid  = threadIdx.x;
  const int lane = tid & 63;
  const int wid  = tid >> 6;   // 0..7
  const int wm   = wid >> 1;   // 0..3  (M wave)
  const int wn   = wid & 1;    // 0..1  (N wave)
  const int q    = lane >> 4;  // quad 0..3
  const int l15  = lane & 15;

  const int m0 = blockIdx.y * BM;
  const int n0 = blockIdx.x * BN;

  // ---- A staging: each thread handles two 16-float groups per K tile ----
  const int ar0 = tid >> 2;          // rows 0..127
  const int ar1 = ar0 + 128;         // rows 128..255
  const int ag  = tid & 3;           // group within row (16 k each)
  const float* pa0 = X + (size_t)(m0 + ar0) * IN_F + ag * 16;
  const float* pa1 = X + (size_t)(m0 + ar1) * IN_F + ag * 16;
  short* wa0 = lA + ar0 * LDK + ag * 16;
  short* wa1 = lA + ar1 * LDK + ag * 16;

  // ---- B staging: each thread unpacks one int32 (16 ternary values) per K tile ----
  const int brow = tid >> 2;         // 0..127
  const int bwrd = tid & 3;          // which int32 within the BK=64 slab
  const int* pb = PW + (size_t)(n0 + brow) * PACKED + bwrd;
  short* wb = lB + brow * LDK + bwrd * 16;

  // ---- MFMA fragment LDS offsets ----
  const int aoff = (wm * 64 + l15) * LDK + q * 8;
  const int boff = (wn * 64 + l15) * LDK + q * 8;

  f32x4 acc[4][4];
#pragma unroll
  for (int i = 0; i < 4; ++i)
#pragma unroll
    for (int j = 0; j < 4; ++j)
      acc[i][j] = f32x4{0.f, 0.f, 0.f, 0.f};

  auto stage_a = [&](const float* p, short* w) {
    f32x4 f0 = *(const f32x4*)(p);
    f32x4 f1 = *(const f32x4*)(p + 4);
    f32x4 f2 = *(const f32x4*)(p + 8);
    f32x4 f3 = *(const f32x4*)(p + 12);
    // slot 2j <- f[j], slot 2j+1 <- f[j+8]
    uint2 u0 = make_uint2(pack_bf2(f0.x, f2.x), pack_bf2(f0.y, f2.y));
    uint2 u1 = make_uint2(pack_bf2(f0.z, f2.z), pack_bf2(f0.w, f2.w));
    uint2 u2 = make_uint2(pack_bf2(f1.x, f3.x), pack_bf2(f1.y, f3.y));
    uint2 u3 = make_uint2(pack_bf2(f1.z, f3.z), pack_bf2(f1.w, f3.w));
    *(uint2*)(w + 0)  = u0;
    *(uint2*)(w + 4)  = u1;
    *(uint2*)(w + 8)  = u2;
    *(uint2*)(w + 12) = u3;
  };

  for (int kt = 0; kt < IN_F / BK; ++kt) {
    stage_a(pa0, wa0);
    stage_a(pa1, wa1);

    // ---- dequant 16 ternary values -> bf16 {-1,0,1} via bit planes ----
    unsigned w   = (unsigned)(*pb);
    unsigned shr = w >> 1;
    unsigned s   = ~(w | shr) & 0x55555555u;        // bit2j = (v==0) -> sign
    unsigned mm  = (shr & 0x55555555u) | s;         // bit2j = (v!=1) -> magnitude
    unsigned d[8];
#pragma unroll
    for (int j = 0; j < 8; ++j) {
      unsigned sj = (s  >> (2 * j)) & 0x00010001u;  // v_j==0 (lo), v_{j+8}==0 (hi)
      unsigned mj = (mm >> (2 * j)) & 0x00010001u;
      d[j] = (sj << 15) | (mj * 0x3F80u);           // 0xBF80 / 0x0000 / 0x3F80 per half
    }
    *(uint2*)(wb + 0)  = make_uint2(d[0], d[1]);
    *(uint2*)(wb + 4)  = make_uint2(d[2], d[3]);
    *(uint2*)(wb + 8)  = make_uint2(d[4], d[5]);
    *(uint2*)(wb + 12) = make_uint2(d[6], d[7]);

    __syncthreads();

#pragma unroll
    for (int ks = 0; ks < 2; ++ks) {
      short8 av[4], bv[4];
#pragma unroll
      for (int i = 0; i < 4; ++i)
        av[i] = *(const short8*)(lA + aoff + i * (16 * LDK) + ks * 32);
#pragma unroll
      for (int i = 0; i < 4; ++i)
        bv[i] = *(const short8*)(lB + boff + i * (16 * LDK) + ks * 32);
#pragma unroll
      for (int i = 0; i < 4; ++i)
#pragma unroll
        for (int j = 0; j < 4; ++j)
          acc[i][j] = __builtin_amdgcn_mfma_f32_16x16x32_bf16(av[i], bv[j], acc[i][j], 0, 0, 0);
    }

    __syncthreads();
    pa0 += BK;
    pa1 += BK;
    pb  += BK / 16;
  }

  // ---- epilogue: C/D layout col=lane&15, row=quad*4+reg; apply `scale` ----
  const float sc = SC[0];
  const int orow = m0 + wm * 64 + q * 4;
  const int ocol = n0 + wn * 64 + l15;
#pragma unroll
  for (int i = 0; i < 4; ++i) {
#pragma unroll
    for (int j = 0; j < 4; ++j) {
      float* po = OUT + (size_t)(orow + i * 16) * OUT_F + (ocol + j * 16);
      po[0 * OUT_F] = acc[i][j].x * sc;
      po[1 * OUT_F] = acc[i][j].y * sc;
      po[2 * OUT_F] = acc[i][j].z * sc;
      po[3 * OUT_F] = acc[i][j].w * sc;
    }
  }
}

extern "C" void kernel_launch(void* const* d_in, const int* in_sizes, int n_in,
                              void* d_out, int out_size, void* d_ws, size_t ws_size,
                              hipStream_t stream) {
  const float* x   = (const float*)d_in[0];
  const int*   pw  = (const int*)d_in[1];
  const float* sc  = (const float*)d_in[2];
  float*       out = (float*)d_out;

  dim3 grid(OUT_F / BN, TOKENS / BM);  // (32, 32) = 1024 blocks
  pbl_kernel<<<grid, dim3(NTHR, 1, 1), 0, stream>>>(x, pw, sc, out);
}

// Round 4
// 489.433 us; speedup vs baseline: 1.1875x; 1.1875x over previous
//
#include <hip/hip_runtime.h>
#include <math.h>

typedef __attribute__((ext_vector_type(4)))  int   i32x4;
typedef __attribute__((ext_vector_type(16))) int   i32x16;
typedef __attribute__((ext_vector_type(4)))  float f32x4;

namespace {
constexpr int IN_F   = 4096;
constexpr int OUT_F  = 4096;
constexpr int TOKENS = 8192;
constexpr int PACKED = IN_F / 16;      // 256 words per weight row

constexpr int BM   = 256;
constexpr int BN   = 128;
constexpr int BK   = 128;              // i8 k per tile; 8 chunks of 16
constexpr int NTHR = 256;              // 4 waves, 2(M) x 2(N), wave tile 128x64
constexpr size_t XQ_BYTES = (size_t)TOKENS * IN_F;   // 33.55 MB in ws
}

// ---------------- pass 1: per-row absmax + i8 quantize ----------------
// One wave per row: 16 chunks x 256 floats (lane*4 within chunk) = 4096 floats.
__global__ __launch_bounds__(256)
void rowquant(const float* __restrict__ X, signed char* __restrict__ XQ,
              float* __restrict__ XS) {
  const int row  = blockIdx.x * 4 + (threadIdx.x >> 6);
  const int lane = threadIdx.x & 63;
  const float* xr = X + (size_t)row * IN_F;

  f32x4 v[16];
  float m = 0.f;
#pragma unroll
  for (int c = 0; c < 16; ++c) {
    v[c] = *(const f32x4*)(xr + c * 256 + lane * 4);
    m = fmaxf(m, fmaxf(fmaxf(fabsf(v[c].x), fabsf(v[c].y)),
                       fmaxf(fabsf(v[c].z), fabsf(v[c].w))));
  }
#pragma unroll
  for (int off = 32; off; off >>= 1) m = fmaxf(m, __shfl_xor(m, off, 64));
  m = fmaxf(m, 1e-5f);
  const float r = 127.f / m;

#pragma unroll
  for (int c = 0; c < 16; ++c) {
    int q0 = (int)rintf(v[c].x * r);
    int q1 = (int)rintf(v[c].y * r);
    int q2 = (int)rintf(v[c].z * r);
    int q3 = (int)rintf(v[c].w * r);
    unsigned d = (q0 & 255) | ((q1 & 255) << 8) | ((q2 & 255) << 16) | ((q3 & 255) << 24);
    *(unsigned*)(XQ + (size_t)row * IN_F + c * 256 + lane * 4) = d;
  }
  if (lane == 0) XS[row] = m;
}

// 16x 2-bit {0,1,2}  ->  16x i8 {-1,0,1}  (4 dwords)
__device__ __forceinline__ i32x4 unpack16(unsigned w) {
  i32x4 r;
#pragma unroll
  for (int g = 0; g < 4; ++g) {
    unsigned t = (w >> (8 * g)) & 0xFFu;
    unsigned s = (t | (t << 6) | (t << 12) | (t << 18)) & 0x03030303u;
    r[g] = (int)((((s | 0x80808080u) - 0x01010101u) ^ 0x80808080u));
  }
  return r;
}

// ---------------- pass 2: i8 GEMM, B unpacked on the fly ----------------
__global__ __launch_bounds__(NTHR, 2)
void gemm_i8(const signed char* __restrict__ XQ, const unsigned* __restrict__ PW,
             const float* __restrict__ XS, const float* __restrict__ SC,
             float* __restrict__ OUT) {
  // A in LDS, chunk-major: offset(m, c) = c*4096 + m*16  (c = k/16 within tile)
  __shared__ signed char lA[BM * BK];

  const int tid  = threadIdx.x;
  const int lane = tid & 63;
  const int w    = tid >> 6;     // 0..3
  const int wm   = w >> 1;       // 0..1
  const int wn   = w & 1;        // 0..1
  const int l31  = lane & 31;
  const int h    = lane >> 5;    // half-wave

  const int m0 = blockIdx.y * BM;
  const int n0 = blockIdx.x * BN;

  i32x16 acc[4][2];
#pragma unroll
  for (int mf = 0; mf < 4; ++mf)
#pragma unroll
    for (int nf = 0; nf < 2; ++nf)
      acc[mf][nf] = (i32x16)(0);

  // B packed-word row bases for this lane's two n-columns
  const unsigned* pb0 = PW + (size_t)(n0 + wn * 64 + 0 * 32 + l31) * PACKED;
  const unsigned* pb1 = PW + (size_t)(n0 + wn * 64 + 1 * 32 + l31) * PACKED;

  for (int kt = 0; kt < IN_F / BK; ++kt) {
    // ---- stage A: wave w handles chunks {2w, 2w+1}, 4 row-blocks each ----
#pragma unroll
    for (int cc = 0; cc < 2; ++cc) {
      const int c = w * 2 + cc;
#pragma unroll
      for (int rb = 0; rb < 4; ++rb) {
        const signed char* src =
            XQ + (size_t)(m0 + rb * 64 + lane) * IN_F + kt * BK + c * 16;
        signed char* dst = lA + c * 4096 + rb * 1024;  // wave-uniform; HW adds lane*16
        __builtin_amdgcn_global_load_lds(
            (const __attribute__((address_space(1))) void*)src,
            (__attribute__((address_space(3))) void*)dst, 16, 0, 0);
      }
    }

    // ---- B words for this kt (8 per lane), L1/L2-resident ----
    unsigned bw0[4], bw1[4];
#pragma unroll
    for (int ks = 0; ks < 4; ++ks) {
      bw0[ks] = pb0[kt * 8 + ks * 2 + h];
      bw1[ks] = pb1[kt * 8 + ks * 2 + h];
    }

    __syncthreads();

#pragma unroll
    for (int ks = 0; ks < 4; ++ks) {
      i32x4 bfr0 = unpack16(bw0[ks]);
      i32x4 bfr1 = unpack16(bw1[ks]);
      i32x4 afr[4];
#pragma unroll
      for (int mf = 0; mf < 4; ++mf)
        afr[mf] = *(const i32x4*)(lA + (ks * 2 + h) * 4096 +
                                  (wm * 128 + mf * 32 + l31) * 16);
#pragma unroll
      for (int mf = 0; mf < 4; ++mf) {
        acc[mf][0] = __builtin_amdgcn_mfma_i32_32x32x32_i8(afr[mf], bfr0, acc[mf][0], 0, 0, 0);
        acc[mf][1] = __builtin_amdgcn_mfma_i32_32x32x32_i8(afr[mf], bfr1, acc[mf][1], 0, 0, 0);
      }
    }
    __syncthreads();
  }

  // ---- epilogue: C/D (32x32): col=lane&31, row=(reg&3)+8*(reg>>2)+4*h ----
  const float sc = SC[0] / 127.f;
#pragma unroll
  for (int mf = 0; mf < 4; ++mf) {
    float fs[16];
#pragma unroll
    for (int r = 0; r < 16; ++r) {
      const int mm = m0 + wm * 128 + mf * 32 + 4 * h + (r & 3) + 8 * (r >> 2);
      fs[r] = sc * XS[mm];
    }
#pragma unroll
    for (int nf = 0; nf < 2; ++nf) {
      const int ncol = n0 + wn * 64 + nf * 32 + l31;
#pragma unroll
      for (int r = 0; r < 16; ++r) {
        const int mm = m0 + wm * 128 + mf * 32 + 4 * h + (r & 3) + 8 * (r >> 2);
        OUT[(size_t)mm * OUT_F + ncol] = (float)acc[mf][nf][r] * fs[r];
      }
    }
  }
}

extern "C" void kernel_launch(void* const* d_in, const int* in_sizes, int n_in,
                              void* d_out, int out_size, void* d_ws, size_t ws_size,
                              hipStream_t stream) {
  const float*    x  = (const float*)d_in[0];
  const unsigned* pw = (const unsigned*)d_in[1];
  const float*    sc = (const float*)d_in[2];
  float*          out = (float*)d_out;

  signed char* xq = (signed char*)d_ws;
  float*       xs = (float*)((char*)d_ws + XQ_BYTES);

  rowquant<<<dim3(TOKENS / 4), dim3(256), 0, stream>>>(x, xq, xs);
  dim3 grid(OUT_F / BN, TOKENS / BM);  // (32, 32)
  gemm_i8<<<grid, dim3(NTHR), 0, stream>>>(xq, pw, xs, sc, out);
}